// Round 10
// baseline (434.662 us; speedup 1.0000x reference)
//
#include <hip/hip_runtime.h>
#include <hip/hip_bf16.h>

typedef __hip_bfloat16 bf16;
typedef unsigned short u16;
typedef unsigned int   u32;

#define NN 3000
#define EE 48000
#define NF 32
#define KEXC 1200
#define KDEN 10800.0f
#define NB 32
#define NT 1024
#define SEG 94           // rows per segment (32 segments)
#define CHT 9            // chunks per thread (chunk = 8 slots)
#define CS  72           // slots per thread
#define NW  36           // packed u32 words per thread
#define DUMMYC 3070u     // gather index guaranteed 0.0f

// ---- workspace offsets ----
#define OFF_CNT 0u       // u32 pool completion counter
#define OFF_TOT 128u     // 32 f32
#define OFF_EXC 256u     // 32 f32
#define ZERO_BYTES 512u
#define OFF_PK   512u    // 36*1024 u32 packed schedule, layout [w][tau]
#define OFF_RST  147968u // 1024 u32 first-row per thread
#define OFF_WINV 152064u // 3000 f32
#define OFF_Y1A  164352u // 32x3000 f32 (column-contiguous per block)
#define OFF_Y2A  548352u
#define OFF_Y1B  932352u
#define OFF_Y2B  1316352u
#define OFF_X1T  1700352u
#define OFF_X2   2084352u  // row-major 3000x32

// ---- runtime dtype detection (validated rounds 2-9) ----
__device__ __forceinline__ bool scalar_is_bf16(const void* hp) {
    return ((const unsigned short*)hp)[0] != 0x0000;   // h==0.5
}
__device__ __forceinline__ bool tensor_is_bf16(const void* xp) {
    const unsigned short* u = (const unsigned short*)xp;
    int cnt = 0;
    for (int k = 0; k < 16; k++) {
        unsigned e = (u[2 * k] >> 7) & 0xFF;
        if (e >= 107 && e <= 147) cnt++;
    }
    return cnt >= 12;
}
__device__ __forceinline__ float ldv(const void* p, int i, bool b16) {
    return b16 ? __bfloat162float(((const bf16*)p)[i]) : ((const float*)p)[i];
}

// ================= 1: CSR + dedup + chunk-aligned packed schedule =================
__global__ void __launch_bounds__(NT)
k_csr(const int* __restrict__ ei, const void* hp, const void* ap,
      float* __restrict__ winv, u32* __restrict__ pkg, u32* __restrict__ rstg) {
    __shared__ int s_deg[3072], sA[3072], sB[3072];
    __shared__ u16 stage[4096], rid[4096], segsl[4096];
    __shared__ int nseg[33], rcs[96], lcur[96];
    __shared__ int s_fl;
    const int t = threadIdx.x, blk = blockIdx.x;

    if (t == 0) s_fl = scalar_is_bf16(hp) ? 1 : 0;
    for (int i = t; i < 3072; i += NT) s_deg[i] = 0;
    __syncthreads();
    const bool sbf = s_fl != 0;
    const float hh = ldv(hp, 0, sbf), aa = ldv(ap, 0, sbf);

    for (int e = t; e < EE; e += NT) atomicAdd(&s_deg[ei[e]], 1);
    __syncthreads();
    for (int i = t; i < 3072; i += NT) sA[i] = s_deg[i];
    __syncthreads();
    {   // Hillis-Steele inclusive scan -> result ends in sA (12 rounds, even)
        int* src = sA; int* dst = sB;
        for (int d = 1; d < 3072; d <<= 1) {
            for (int i = t; i < 3072; i += NT) dst[i] = src[i] + ((i >= d) ? src[i - d] : 0);
            __syncthreads();
            int* tmp = src; src = dst; dst = tmp;
        }
    }
    int* INC = sA;
#define RPEX(r) ((r) == 0 ? 0 : INC[(r) - 1])

    if (blk == 0)
        for (int i = t; i < NN; i += NT)
            winv[i] = 1.0f / (hh * ((float)s_deg[i] - aa));

    // chunk machine per segment -> thread counts
    if (t < 32) {
        int pos = 0, rA2 = t * SEG, rB2 = (rA2 + SEG < NN) ? (rA2 + SEG) : NN;
        for (int r = rA2; r < rB2; r++) {
            int c = (s_deg[r] + 7) >> 3;
            int rem = CHT - (pos % CHT);
            if (c > rem) pos += rem;
            pos += c;
        }
        lcur[t] = (pos + CHT - 1) / CHT;
    }
    __syncthreads();
    if (t == 0) {
        int acc = 0;
        for (int s = 0; s < 32; s++) { int v = lcur[s]; nseg[s] = acc; acc += v; }
        nseg[32] = acc;
    }
    __syncthreads();

    const int r0 = blk * SEG;
    const int r1 = (r0 + SEG < NN) ? (r0 + SEG) : NN;
    const int th0 = nseg[blk];
    const int th1 = nseg[blk + 1];
    const int span = th1 - th0;
    const int base = RPEX(r0);
    const int cnt  = RPEX(r1) - base;

    // detailed machine for own segment
    if (t == 0) {
        int pos = 0;
        for (int rr = 0; rr < (r1 - r0); rr++) {
            int c = (s_deg[r0 + rr] + 7) >> 3;
            int rem = CHT - (pos % CHT);
            if (c > rem) pos += rem;
            if ((pos % CHT) == 0 && (th0 + pos / CHT) < NT)
                rstg[th0 + pos / CHT] = (u32)(r0 + rr);
            rcs[rr] = pos;
            pos += c;
        }
    }
    __syncthreads();
    if (t < 96) lcur[t] = 0;
    __syncthreads();
    for (int e = t; e < EE; e += NT) {
        int r = ei[e];
        if (r >= r0 && r < r1) {
            int pos = atomicAdd(&lcur[r - r0], 1);
            stage[(RPEX(r) - base) + pos] = (u16)ei[EE + e];
        }
    }
    __syncthreads();
    for (int rr = t; rr < (r1 - r0); rr += NT) {
        int s0 = RPEX(r0 + rr) - base, s1 = RPEX(r0 + rr + 1) - base;
        for (int s2 = s0; s2 < s1; s2++) rid[s2] = (u16)rr;
    }
    __syncthreads();
    // dedup in place: dups -> DUMMYC (first occurrence kept, never rewritten)
    for (int ls = t; ls < cnt; ls += NT) {
        int rr = rid[ls];
        int rs = RPEX(r0 + rr) - base;
        u16 c = stage[ls];
        bool dup = false;
        for (int ls2 = rs; ls2 < ls; ls2++) dup |= (stage[ls2] == c);
        if (dup) stage[ls] = (u16)DUMMYC;
    }
    __syncthreads();
    for (int idx = t; idx < span * CS; idx += NT) segsl[idx] = (u16)DUMMYC;
    __syncthreads();
    for (int ls = t; ls < cnt; ls += NT) {
        int rr = rid[ls];
        int o = ls - (RPEX(r0 + rr) - base);
        segsl[rcs[rr] * 8 + o] = stage[ls];
    }
    __syncthreads();
    for (int rr = t; rr < (r1 - r0); rr += NT) {
        int c = (s_deg[r0 + rr] + 7) >> 3;
        segsl[(rcs[rr] + c) * 8 - 1] |= (u16)0x8000u;   // flush on row's last slot
    }
    __syncthreads();
    // emit packed words [w][tau]
    for (int idx = t; idx < span * NW; idx += NT) {
        int tl = idx / NW, w = idx % NW;
        int tau = th0 + tl;
        if (tau < NT)
            pkg[w * NT + tau] = (u32)segsl[tl * CS + 2 * w] | ((u32)segsl[tl * CS + 2 * w + 1] << 16);
    }
    if (blk == 31) {       // pad threads: no flush bits, rstg = 0
        const u32 DW = DUMMYC | (DUMMYC << 16);
        for (int tau = nseg[32] + t; tau < NT; tau += NT) rstg[tau] = 0;
        for (int idx = t; idx < (NT - nseg[32]) * NW; idx += NT) {
            int tau = nseg[32] + idx / NW, w = idx % NW;
            if (tau < NT) pkg[w * NT + tau] = DW;
        }
    }
#undef RPEX
}

// ================= 2: Cayley chains (one feature column per block) =================
// Schedule is deliberately STREAMED from L2 each step via volatile loads —
// r8/r9 proved a register-resident schedule spills (compiler caps at 64 VGPR
// for 1024-thread blocks) and scratch traffic dominates. 36 coalesced dwords/
// thread/step = 147 KB/block/step from L2, hidden across 16 waves.
__global__ void __launch_bounds__(NT)
k_chains(const void* __restrict__ xg, int cv, const void* hp,
         const u32* __restrict__ pkg, const u32* __restrict__ rstg,
         const float* __restrict__ winv,
         const void* __restrict__ Wr, const void* __restrict__ Wa, const void* __restrict__ Wb,
         const float* __restrict__ y1in, const float* __restrict__ y2in,
         float* __restrict__ x1T,
         float* __restrict__ y1o, float* __restrict__ y2o) {
    __shared__ float SM[15360];   // 60 KB aliased blob
    __shared__ int s_fl[2];
    float* s_y  = SM + 0;
    float* s_bc = SM + 3072;
    float* zA   = SM + 6144;
    float* zB   = SM + 9216;
    float* s_w  = SM + 12288;
    float* wst  = SM + 3072;      // aliases s_bc (re-init after use)
    const int t = threadIdx.x, blk = blockIdx.x;

    if (t == 0) { s_fl[0] = tensor_is_bf16(xg) ? 1 : 0; s_fl[1] = scalar_is_bf16(hp) ? 1 : 0; }
    __syncthreads();
    const bool tb  = s_fl[0] != 0;
    const float hh = ldv(hp, 0, s_fl[1] != 0);

    const int row0 = (int)rstg[t];
    volatile const u32* pkv = pkg + t;     // per-thread column; volatile = no hoist/spill

    // ---- init column f = blk ----
    if (cv == 0) {
#pragma unroll
        for (int k = 0; k < 3; k++) {
            int i = t + k * NT;
            float v = (i < NN) ? ldv(xg, i * NF + blk, tb) : 0.0f;
            float w = (i < NN) ? winv[i] : 0.0f;
            s_y[i] = v; s_w[i] = w; s_bc[i] = 0.f; zA[i] = w * v; zB[i] = 0.f;
        }
    } else {
        if (t < 32)      wst[t] = ldv(Wr, blk * 32 + t, tb);
        else if (t < 64) wst[t] = 2.0f * ldv(Wa, blk * 32 + (t - 32), tb);
        else if (t < 96) wst[t] = 2.0f * ldv(Wb, blk * 32 + (t - 64), tb);
        __syncthreads();
        float v[3] = {0.f, 0.f, 0.f};
#pragma unroll
        for (int k = 0; k < 3; k++) {
            int i = t + k * NT;
            if (i < NN) {
                float a = 0.f;
#pragma unroll
                for (int f = 0; f < NF; f++)
                    a += ldv(xg, i * NF + f, tb) * wst[f]
                       + y1in[f * NN + i] * wst[32 + f]
                       + y2in[f * NN + i] * wst[64 + f];
                v[k] = fmaxf(a, 0.f);
                x1T[blk * NN + i] = v[k];
            }
        }
        __syncthreads();   // wst reads done before s_bc reuse
#pragma unroll
        for (int k = 0; k < 3; k++) {
            int i = t + k * NT;
            float w = (i < NN) ? winv[i] : 0.0f;
            s_y[i] = (i < NN) ? v[k] : 0.f;
            s_w[i] = w; s_bc[i] = 0.f; zA[i] = w * s_y[i]; zB[i] = 0.f;
        }
    }
    __syncthreads();

    float* cur = zA;
    float* nxt = zB;
#pragma unroll 1
    for (int ord = 0; ord < 2; ord++) {
#pragma unroll 1
        for (int step = 0; step < 6; step++) {     // 0 = b-step, 1..5 = Jacobi
            const float* gs = (step == 0) ? s_y : cur;
            float acc = 0.f;
            int rc = row0;
#pragma unroll
            for (int c = 0; c < CHT; c++) {
                u32 w0 = pkv[(c * 4 + 0) * NT];
                u32 w1 = pkv[(c * 4 + 1) * NT];
                u32 w2 = pkv[(c * 4 + 2) * NT];
                u32 w3 = pkv[(c * 4 + 3) * NT];
                acc += gs[w0 & 0xFFFu] + gs[(w0 >> 16) & 0xFFFu]
                     + gs[w1 & 0xFFFu] + gs[(w1 >> 16) & 0xFFFu]
                     + gs[w2 & 0xFFFu] + gs[(w2 >> 16) & 0xFFFu]
                     + gs[w3 & 0xFFFu] + gs[(w3 >> 16) & 0xFFFu];
                if (w3 & 0x80000000u) {            // flush: row complete
                    float wr = s_w[rc];
                    if (step == 0) {
                        float nb = s_y[rc] - hh * wr * acc;   // y - (1/dvals)*sum
                        s_bc[rc] = nb;
                        nxt[rc] = wr * nb;
                    } else {
                        float yn = s_bc[rc] + acc;            // b + J*y
                        nxt[rc] = wr * yn;
                        if (step == 5) s_y[rc] = yn;
                    }
                    rc++; acc = 0.f;
                }
            }
            float* tmp = cur; cur = nxt; nxt = tmp;
            __syncthreads();
        }
        float* yo = (ord == 0) ? y1o : y2o;
#pragma unroll
        for (int k = 0; k < 3; k++) {
            int i = t + k * NT;
            if (i < NN) yo[blk * NN + i] = s_y[i];   // contiguous plain stores
        }
    }
}

// ================= 3: GEMM2 (x2 = relu(x1@Wr1^T + 2y1@Wa1^T + 2y2@Wb1^T)) =========
__global__ void __launch_bounds__(256)
k_gemm(const float* __restrict__ x1T,
       const void* __restrict__ Wr, const void* __restrict__ Wa, const void* __restrict__ Wb,
       const float* __restrict__ y1T, const float* __restrict__ y2T,
       float* __restrict__ x2) {
    __shared__ float sWr[1024], sWa[1024], sWb[1024];
    __shared__ int s_fl;
    const int t = threadIdx.x;
    if (t == 0) s_fl = tensor_is_bf16(Wr) ? 1 : 0;
    __syncthreads();
    const bool wtb = s_fl != 0;
    for (int i = t; i < 1024; i += 256) {
        sWr[i] = ldv(Wr, i, wtb);
        sWa[i] = ldv(Wa, i, wtb);
        sWb[i] = ldv(Wb, i, wtb);
    }
    __syncthreads();
    int w = blockIdx.x * 256 + t;
    if (w >= NN * 4) return;
    int i = w >> 2, q = (w & 3) * 8;
    float a[8];
#pragma unroll
    for (int o = 0; o < 8; o++) a[o] = 0.f;
#pragma unroll
    for (int f = 0; f < NF; f++) {
        float xv = x1T[f * NN + i];
        float v1 = 2.0f * y1T[f * NN + i];
        float v2 = 2.0f * y2T[f * NN + i];
#pragma unroll
        for (int o = 0; o < 8; o++)
            a[o] += xv * sWr[(q + o) * 32 + f] + v1 * sWa[(q + o) * 32 + f] + v2 * sWb[(q + o) * 32 + f];
    }
    float4 r0, r1;
    r0.x = fmaxf(a[0], 0.f); r0.y = fmaxf(a[1], 0.f); r0.z = fmaxf(a[2], 0.f); r0.w = fmaxf(a[3], 0.f);
    r1.x = fmaxf(a[4], 0.f); r1.y = fmaxf(a[5], 0.f); r1.z = fmaxf(a[6], 0.f); r1.w = fmaxf(a[7], 0.f);
    *(float4*)(x2 + i * NF + q)     = r0;
    *(float4*)(x2 + i * NF + q + 4) = r1;
}

// ================= 4: pooling + fused final linear =================
__global__ void __launch_bounds__(512)
k_pool(const float* __restrict__ x2, const void* __restrict__ pwp,
       const void* __restrict__ lwp, const void* __restrict__ lbp,
       u32* __restrict__ cntg, float* __restrict__ totf, float* __restrict__ excf,
       void* __restrict__ outp) {
    __shared__ float s_s[3072];
    __shared__ float red[512];
    __shared__ int rnk[96];
    __shared__ int s_fl, s_last;
    const int t = threadIdx.x, blk = blockIdx.x;
    const int PNT = 512;

    if (t == 0) s_fl = tensor_is_bf16(pwp) ? 1 : 0;
    __syncthreads();
    const bool tb = s_fl != 0;
    float pw[32];
    float nrm2 = 0.f;
#pragma unroll
    for (int f = 0; f < NF; f++) { pw[f] = ldv(pwp, f, tb); nrm2 += pw[f] * pw[f]; }
    const float nrm = sqrtf(nrm2);

    for (int i = t; i < 3072; i += PNT) {
        if (i < NN) {
            const float* xr = x2 + i * NF;
            float d = 0.f;
#pragma unroll
            for (int f = 0; f < NF; f++) d += xr[f] * pw[f];
            s_s[i] = tanhf(d / nrm);
        } else s_s[i] = 0.f;
    }
    if (t < 96) rnk[t] = 0;
    __syncthreads();

    const int j0 = blk * SEG;
    const int j1 = (j0 + SEG < NN) ? (j0 + SEG) : NN;
    // exact top_k rank (key = (score asc, index desc)); only negatives matter
    for (int u = t; u < SEG * 5; u += PNT) {
        int lr = u / 5, i = j0 + lr;
        if (i < j1) {
            float si = s_s[i];
            if (si < 0.f) {
                int seg = (u % 5) * 600;
                int c2 = 0;
                for (int j = seg; j < seg + 600 && j < NN; j++) {
                    float sj = s_s[j];
                    c2 += (sj < si) || ((sj == si) && (j > i));
                }
                if (c2) atomicAdd(&rnk[lr], c2);
            }
        }
    }
    __syncthreads();

    int f = t & 31, rl = t >> 5;
    float at = 0.f, ae = 0.f;
    for (int lr = rl; lr < SEG; lr += 16) {
        int i = j0 + lr;
        if (i < j1) {
            float si = s_s[i];
            float term = x2[i * NF + f] * si;
            at += term;
            if (si < 0.f && rnk[lr] < KEXC) ae += term;
        }
    }
    red[t] = at; __syncthreads();
    for (int s = 256; s >= 32; s >>= 1) { if (t < s) red[t] += red[t + s]; __syncthreads(); }
    if (t < 32) atomicAdd(&totf[t], red[t]);
    __syncthreads();
    red[t] = ae; __syncthreads();
    for (int s = 256; s >= 32; s >>= 1) { if (t < s) red[t] += red[t + s]; __syncthreads(); }
    if (t < 32) atomicAdd(&excf[t], red[t]);
    __syncthreads();

    if (t == 0) {
        __threadfence();
        u32 old = atomicAdd(cntg, 1u);
        s_last = (old == NB - 1) ? 1 : 0;
    }
    __syncthreads();
    if (s_last) {
        __threadfence();
        if (t < 8) {
            float o = ldv(lbp, t, tb);
            for (int ff = 0; ff < NF; ff++) {
                float tv = __hip_atomic_load(&totf[ff], __ATOMIC_RELAXED, __HIP_MEMORY_SCOPE_AGENT);
                float ev = __hip_atomic_load(&excf[ff], __ATOMIC_RELAXED, __HIP_MEMORY_SCOPE_AGENT);
                o += ((tv - ev) / KDEN) * ldv(lwp, t * 32 + ff, tb);
            }
            if (tb) ((bf16*)outp)[t] = __float2bfloat16(o);
            else    ((float*)outp)[t] = o;
        }
    }
}

extern "C" void kernel_launch(void* const* d_in, const int* in_sizes, int n_in,
                              void* d_out, int out_size, void* d_ws, size_t ws_size,
                              hipStream_t stream) {
    const void* x   = d_in[0];
    const int*  ei  = (const int*)d_in[1];
    const void* hp  = d_in[2];
    const void* ap  = d_in[3];
    const void* Wr0 = d_in[4];
    const void* Wa0 = d_in[5];
    const void* Wb0 = d_in[6];
    const void* Wr1 = d_in[7];
    const void* Wa1 = d_in[8];
    const void* Wb1 = d_in[9];
    const void* pw  = d_in[10];
    const void* lw  = d_in[11];
    const void* lb  = d_in[12];
    char* ws = (char*)d_ws;

    u32*   cntg = (u32*)(ws + OFF_CNT);
    float* totf = (float*)(ws + OFF_TOT);
    float* excf = (float*)(ws + OFF_EXC);
    u32*   pkg  = (u32*)(ws + OFF_PK);
    u32*   rstg = (u32*)(ws + OFF_RST);
    float* winv = (float*)(ws + OFF_WINV);
    float* y1a  = (float*)(ws + OFF_Y1A);
    float* y2a  = (float*)(ws + OFF_Y2A);
    float* y1b  = (float*)(ws + OFF_Y1B);
    float* y2b  = (float*)(ws + OFF_Y2B);
    float* x1T  = (float*)(ws + OFF_X1T);
    float* x2   = (float*)(ws + OFF_X2);

    hipMemsetAsync(ws, 0, ZERO_BYTES, stream);
    k_csr   <<<dim3(32), dim3(NT),  0, stream>>>(ei, hp, ap, winv, pkg, rstg);
    k_chains<<<dim3(32), dim3(NT),  0, stream>>>(x, 0, hp, pkg, rstg, winv,
                                                 Wr0, Wa0, Wb0, y1a, y2a, x1T, y1a, y2a);
    k_chains<<<dim3(32), dim3(NT),  0, stream>>>(x, 1, hp, pkg, rstg, winv,
                                                 Wr0, Wa0, Wb0, y1a, y2a, x1T, y1b, y2b);
    k_gemm  <<<dim3(47), dim3(256), 0, stream>>>(x1T, Wr1, Wa1, Wb1, y1b, y2b, x2);
    k_pool  <<<dim3(32), dim3(512), 0, stream>>>(x2, pw, lw, lb, cntg, totf, excf, d_out);
}

// Round 11
// 392.255 us; speedup vs baseline: 1.1081x; 1.1081x over previous
//
#include <hip/hip_runtime.h>
#include <hip/hip_bf16.h>

typedef __hip_bfloat16 bf16;
typedef unsigned short u16;
typedef unsigned int   u32;

#define NN 3000
#define EE 48000
#define NF 32
#define KEXC 1200
#define KDEN 10800.0f
#define NB 32
#define NT 1024
#define SEG 94           // rows per segment (32 segments)
#define CHT 9            // chunks per thread (chunk = 8 slots)
#define CS  72           // slots per thread
#define NW  36           // packed u32 words per thread
#define DUMMYC 3070u     // gather index guaranteed 0.0f

// ---- workspace offsets ----
#define OFF_CNT 0u       // u32 pool completion counter
#define OFF_TOT 128u     // 32 f32
#define OFF_EXC 256u     // 32 f32
#define ZERO_BYTES 512u
#define OFF_PK   512u    // 36864 u32 packed schedule, chunk-major [c][tau][m]
#define OFF_RST  147968u // 1024 u32 first-row per thread
#define OFF_WINV 152064u // 3000 f32
#define OFF_Y1A  164352u // 32x3000 f32 (column-contiguous per block)
#define OFF_Y2A  548352u
#define OFF_Y1B  932352u
#define OFF_Y2B  1316352u
#define OFF_X1T  1700352u
#define OFF_X2   2084352u  // row-major 3000x32

// ---- runtime dtype detection (validated rounds 2-10) ----
__device__ __forceinline__ bool scalar_is_bf16(const void* hp) {
    return ((const unsigned short*)hp)[0] != 0x0000;   // h==0.5
}
__device__ __forceinline__ bool tensor_is_bf16(const void* xp) {
    const unsigned short* u = (const unsigned short*)xp;
    int cnt = 0;
    for (int k = 0; k < 16; k++) {
        unsigned e = (u[2 * k] >> 7) & 0xFF;
        if (e >= 107 && e <= 147) cnt++;
    }
    return cnt >= 12;
}
__device__ __forceinline__ float ldv(const void* p, int i, bool b16) {
    return b16 ? __bfloat162float(((const bf16*)p)[i]) : ((const float*)p)[i];
}

// ================= 1: CSR + dedup + chunk-aligned packed schedule =================
__global__ void __launch_bounds__(NT)
k_csr(const int* __restrict__ ei, const void* hp, const void* ap,
      float* __restrict__ winv, u32* __restrict__ pkg, u32* __restrict__ rstg) {
    __shared__ int s_deg[3072], sA[3072], sB[3072];
    __shared__ u16 stage[4096], rid[4096], segsl[4096];
    __shared__ int nseg[33], rcs[96], lcur[96];
    __shared__ int s_fl;
    const int t = threadIdx.x, blk = blockIdx.x;

    if (t == 0) s_fl = scalar_is_bf16(hp) ? 1 : 0;
    for (int i = t; i < 3072; i += NT) s_deg[i] = 0;
    __syncthreads();
    const bool sbf = s_fl != 0;
    const float hh = ldv(hp, 0, sbf), aa = ldv(ap, 0, sbf);

    for (int e = t; e < EE; e += NT) atomicAdd(&s_deg[ei[e]], 1);
    __syncthreads();
    for (int i = t; i < 3072; i += NT) sA[i] = s_deg[i];
    __syncthreads();
    {   // Hillis-Steele inclusive scan -> result ends in sA (12 rounds, even)
        int* src = sA; int* dst = sB;
        for (int d = 1; d < 3072; d <<= 1) {
            for (int i = t; i < 3072; i += NT) dst[i] = src[i] + ((i >= d) ? src[i - d] : 0);
            __syncthreads();
            int* tmp = src; src = dst; dst = tmp;
        }
    }
    int* INC = sA;
#define RPEX(r) ((r) == 0 ? 0 : INC[(r) - 1])

    if (blk == 0)
        for (int i = t; i < NN; i += NT)
            winv[i] = 1.0f / (hh * ((float)s_deg[i] - aa));

    // chunk machine per segment -> thread counts
    if (t < 32) {
        int pos = 0, rA2 = t * SEG, rB2 = (rA2 + SEG < NN) ? (rA2 + SEG) : NN;
        for (int r = rA2; r < rB2; r++) {
            int c = (s_deg[r] + 7) >> 3;
            int rem = CHT - (pos % CHT);
            if (c > rem) pos += rem;
            pos += c;
        }
        lcur[t] = (pos + CHT - 1) / CHT;
    }
    __syncthreads();
    if (t == 0) {
        int acc = 0;
        for (int s = 0; s < 32; s++) { int v = lcur[s]; nseg[s] = acc; acc += v; }
        nseg[32] = acc;
    }
    __syncthreads();

    const int r0 = blk * SEG;
    const int r1 = (r0 + SEG < NN) ? (r0 + SEG) : NN;
    const int th0 = nseg[blk];
    const int th1 = nseg[blk + 1];
    const int span = th1 - th0;
    const int base = RPEX(r0);
    const int cnt  = RPEX(r1) - base;

    // detailed machine for own segment
    if (t == 0) {
        int pos = 0;
        for (int rr = 0; rr < (r1 - r0); rr++) {
            int c = (s_deg[r0 + rr] + 7) >> 3;
            int rem = CHT - (pos % CHT);
            if (c > rem) pos += rem;
            if ((pos % CHT) == 0 && (th0 + pos / CHT) < NT)
                rstg[th0 + pos / CHT] = (u32)(r0 + rr);
            rcs[rr] = pos;
            pos += c;
        }
    }
    __syncthreads();
    if (t < 96) lcur[t] = 0;
    __syncthreads();
    for (int e = t; e < EE; e += NT) {
        int r = ei[e];
        if (r >= r0 && r < r1) {
            int pos = atomicAdd(&lcur[r - r0], 1);
            stage[(RPEX(r) - base) + pos] = (u16)ei[EE + e];
        }
    }
    __syncthreads();
    for (int rr = t; rr < (r1 - r0); rr += NT) {
        int s0 = RPEX(r0 + rr) - base, s1 = RPEX(r0 + rr + 1) - base;
        for (int s2 = s0; s2 < s1; s2++) rid[s2] = (u16)rr;
    }
    __syncthreads();
    // dedup in place: dups -> DUMMYC (first occurrence kept, never rewritten)
    for (int ls = t; ls < cnt; ls += NT) {
        int rr = rid[ls];
        int rs = RPEX(r0 + rr) - base;
        u16 c = stage[ls];
        bool dup = false;
        for (int ls2 = rs; ls2 < ls; ls2++) dup |= (stage[ls2] == c);
        if (dup) stage[ls] = (u16)DUMMYC;
    }
    __syncthreads();
    for (int idx = t; idx < span * CS; idx += NT) segsl[idx] = (u16)DUMMYC;
    __syncthreads();
    for (int ls = t; ls < cnt; ls += NT) {
        int rr = rid[ls];
        int o = ls - (RPEX(r0 + rr) - base);
        segsl[rcs[rr] * 8 + o] = stage[ls];
    }
    __syncthreads();
    for (int rr = t; rr < (r1 - r0); rr += NT) {
        int c = (s_deg[r0 + rr] + 7) >> 3;
        segsl[(rcs[rr] + c) * 8 - 1] |= (u16)0x8000u;   // flush on row's last slot
    }
    __syncthreads();
    // emit packed words, CHUNK-MAJOR layout: pkg[c*4096 + tau*4 + m]
    // (one uint4 per chunk per thread; lane i reads base+16i -> ideal coalescing)
    for (int idx = t; idx < span * NW; idx += NT) {
        int tl = idx / NW, w = idx % NW;
        int tau = th0 + tl;
        if (tau < NT) {
            int c = w >> 2, m = w & 3;
            pkg[c * 4096 + tau * 4 + m] =
                (u32)segsl[tl * CS + 2 * w] | ((u32)segsl[tl * CS + 2 * w + 1] << 16);
        }
    }
    if (blk == 31) {       // pad threads: no flush bits, rstg = 0
        const u32 DW = DUMMYC | (DUMMYC << 16);
        for (int tau = nseg[32] + t; tau < NT; tau += NT) rstg[tau] = 0;
        for (int idx = t; idx < (NT - nseg[32]) * NW; idx += NT) {
            int tau = nseg[32] + idx / NW, w = idx % NW;
            if (tau < NT) {
                int c = w >> 2, m = w & 3;
                pkg[c * 4096 + tau * 4 + m] = DW;
            }
        }
    }
#undef RPEX
}

// ================= 2: Cayley chains (one feature column per block) =================
// Schedule streamed from L2 as one coalesced uint4 per chunk, software-pipelined
// 2 chunks ahead with unroll-1 loop -> ~12 live regs, no spill (r8-r10 lesson).
__global__ void __launch_bounds__(NT)
k_chains(const void* __restrict__ xg, int cv, const void* hp,
         const u32* __restrict__ pkg, const u32* __restrict__ rstg,
         const float* __restrict__ winv,
         const void* __restrict__ Wr, const void* __restrict__ Wa, const void* __restrict__ Wb,
         const float* __restrict__ y1in, const float* __restrict__ y2in,
         float* __restrict__ x1T,
         float* __restrict__ y1o, float* __restrict__ y2o) {
    __shared__ float SM[15360];   // 60 KB aliased blob
    __shared__ int s_fl[2];
    float* s_y  = SM + 0;
    float* s_bc = SM + 3072;
    float* zA   = SM + 6144;
    float* zB   = SM + 9216;
    float* s_w  = SM + 12288;
    float* wst  = SM + 3072;      // aliases s_bc (re-init after use)
    const int t = threadIdx.x, blk = blockIdx.x;

    if (t == 0) { s_fl[0] = tensor_is_bf16(xg) ? 1 : 0; s_fl[1] = scalar_is_bf16(hp) ? 1 : 0; }
    __syncthreads();
    const bool tb  = s_fl[0] != 0;
    const float hh = ldv(hp, 0, s_fl[1] != 0);

    const int row0 = (int)rstg[t];
    const uint4* pk4 = (const uint4*)pkg;   // chunk c, thread t -> pk4[c*1024 + t]

    // ---- init column f = blk ----
    if (cv == 0) {
#pragma unroll
        for (int k = 0; k < 3; k++) {
            int i = t + k * NT;
            float v = (i < NN) ? ldv(xg, i * NF + blk, tb) : 0.0f;
            float w = (i < NN) ? winv[i] : 0.0f;
            s_y[i] = v; s_w[i] = w; s_bc[i] = 0.f; zA[i] = 0.f; zB[i] = 0.f;
        }
    } else {
        if (t < 32)      wst[t] = ldv(Wr, blk * 32 + t, tb);
        else if (t < 64) wst[t] = 2.0f * ldv(Wa, blk * 32 + (t - 32), tb);
        else if (t < 96) wst[t] = 2.0f * ldv(Wb, blk * 32 + (t - 64), tb);
        __syncthreads();
        float v[3] = {0.f, 0.f, 0.f};
#pragma unroll
        for (int k = 0; k < 3; k++) {
            int i = t + k * NT;
            if (i < NN) {
                float a = 0.f;
#pragma unroll
                for (int f = 0; f < NF; f++)
                    a += ldv(xg, i * NF + f, tb) * wst[f]
                       + y1in[f * NN + i] * wst[32 + f]
                       + y2in[f * NN + i] * wst[64 + f];
                v[k] = fmaxf(a, 0.f);
                x1T[blk * NN + i] = v[k];
            }
        }
        __syncthreads();   // wst reads done before s_bc reuse
#pragma unroll
        for (int k = 0; k < 3; k++) {
            int i = t + k * NT;
            float w = (i < NN) ? winv[i] : 0.0f;
            s_y[i] = (i < NN) ? v[k] : 0.f;
            s_w[i] = w; s_bc[i] = 0.f; zA[i] = 0.f; zB[i] = 0.f;
        }
    }
    __syncthreads();

    float* cur = zA;
    float* nxt = zB;
#pragma unroll 1
    for (int ord = 0; ord < 2; ord++) {
#pragma unroll 1
        for (int step = 0; step < 6; step++) {     // 0 = b-step, 1..5 = Jacobi
            const float* gs = (step == 0) ? s_y : cur;
            uint4 w0 = pk4[t];                     // chunk 0
            uint4 w1 = pk4[1024 + t];              // chunk 1
            float acc = 0.f;
            int rc = row0;
#pragma unroll 1
            for (int c = 0; c < CHT; c++) {
                int cn = (c + 2 < CHT) ? (c + 2) : c;      // uniform select
                uint4 wn = pk4[cn * 1024 + t];             // prefetch 2 ahead
                acc += gs[w0.x & 0xFFFu] + gs[(w0.x >> 16) & 0xFFFu]
                     + gs[w0.y & 0xFFFu] + gs[(w0.y >> 16) & 0xFFFu]
                     + gs[w0.z & 0xFFFu] + gs[(w0.z >> 16) & 0xFFFu]
                     + gs[w0.w & 0xFFFu] + gs[(w0.w >> 16) & 0xFFFu];
                if (w0.w & 0x80000000u) {          // flush: row complete
                    float wr = s_w[rc];
                    if (step == 0) {
                        float nb = s_y[rc] - hh * wr * acc;   // y - (1/dvals)*sum
                        s_bc[rc] = nb;
                        nxt[rc] = wr * nb;
                    } else {
                        float yn = s_bc[rc] + acc;            // b + J*y
                        nxt[rc] = wr * yn;
                        if (step == 5) s_y[rc] = yn;
                    }
                    rc++; acc = 0.f;
                }
                w0 = w1; w1 = wn;
            }
            float* tmp = cur; cur = nxt; nxt = tmp;
            __syncthreads();
        }
        float* yo = (ord == 0) ? y1o : y2o;
#pragma unroll
        for (int k = 0; k < 3; k++) {
            int i = t + k * NT;
            if (i < NN) yo[blk * NN + i] = s_y[i];   // contiguous plain stores
        }
    }
}

// ================= 3: GEMM2 (x2 = relu(x1@Wr1^T + 2y1@Wa1^T + 2y2@Wb1^T)) =========
__global__ void __launch_bounds__(256)
k_gemm(const float* __restrict__ x1T,
       const void* __restrict__ Wr, const void* __restrict__ Wa, const void* __restrict__ Wb,
       const float* __restrict__ y1T, const float* __restrict__ y2T,
       float* __restrict__ x2) {
    __shared__ float sWr[1024], sWa[1024], sWb[1024];
    __shared__ int s_fl;
    const int t = threadIdx.x;
    if (t == 0) s_fl = tensor_is_bf16(Wr) ? 1 : 0;
    __syncthreads();
    const bool wtb = s_fl != 0;
    for (int i = t; i < 1024; i += 256) {
        sWr[i] = ldv(Wr, i, wtb);
        sWa[i] = ldv(Wa, i, wtb);
        sWb[i] = ldv(Wb, i, wtb);
    }
    __syncthreads();
    int w = blockIdx.x * 256 + t;
    if (w >= NN * 4) return;
    int i = w >> 2, q = (w & 3) * 8;
    float a[8];
#pragma unroll
    for (int o = 0; o < 8; o++) a[o] = 0.f;
#pragma unroll
    for (int f = 0; f < NF; f++) {
        float xv = x1T[f * NN + i];
        float v1 = 2.0f * y1T[f * NN + i];
        float v2 = 2.0f * y2T[f * NN + i];
#pragma unroll
        for (int o = 0; o < 8; o++)
            a[o] += xv * sWr[(q + o) * 32 + f] + v1 * sWa[(q + o) * 32 + f] + v2 * sWb[(q + o) * 32 + f];
    }
    float4 r0, r1;
    r0.x = fmaxf(a[0], 0.f); r0.y = fmaxf(a[1], 0.f); r0.z = fmaxf(a[2], 0.f); r0.w = fmaxf(a[3], 0.f);
    r1.x = fmaxf(a[4], 0.f); r1.y = fmaxf(a[5], 0.f); r1.z = fmaxf(a[6], 0.f); r1.w = fmaxf(a[7], 0.f);
    *(float4*)(x2 + i * NF + q)     = r0;
    *(float4*)(x2 + i * NF + q + 4) = r1;
}

// ================= 4: pooling + fused final linear =================
__global__ void __launch_bounds__(512)
k_pool(const float* __restrict__ x2, const void* __restrict__ pwp,
       const void* __restrict__ lwp, const void* __restrict__ lbp,
       u32* __restrict__ cntg, float* __restrict__ totf, float* __restrict__ excf,
       void* __restrict__ outp) {
    __shared__ float s_s[3072];
    __shared__ float red[512];
    __shared__ int rnk[96];
    __shared__ int s_fl, s_last;
    const int t = threadIdx.x, blk = blockIdx.x;
    const int PNT = 512;

    if (t == 0) s_fl = tensor_is_bf16(pwp) ? 1 : 0;
    __syncthreads();
    const bool tb = s_fl != 0;
    float pw[32];
    float nrm2 = 0.f;
#pragma unroll
    for (int f = 0; f < NF; f++) { pw[f] = ldv(pwp, f, tb); nrm2 += pw[f] * pw[f]; }
    const float nrm = sqrtf(nrm2);

    for (int i = t; i < 3072; i += PNT) {
        if (i < NN) {
            const float* xr = x2 + i * NF;
            float d = 0.f;
#pragma unroll
            for (int f = 0; f < NF; f++) d += xr[f] * pw[f];
            s_s[i] = tanhf(d / nrm);
        } else s_s[i] = 0.f;
    }
    if (t < 96) rnk[t] = 0;
    __syncthreads();

    const int j0 = blk * SEG;
    const int j1 = (j0 + SEG < NN) ? (j0 + SEG) : NN;
    // exact top_k rank (key = (score asc, index desc)); only negatives matter
    for (int u = t; u < SEG * 5; u += PNT) {
        int lr = u / 5, i = j0 + lr;
        if (i < j1) {
            float si = s_s[i];
            if (si < 0.f) {
                int seg = (u % 5) * 600;
                int c2 = 0;
                for (int j = seg; j < seg + 600 && j < NN; j++) {
                    float sj = s_s[j];
                    c2 += (sj < si) || ((sj == si) && (j > i));
                }
                if (c2) atomicAdd(&rnk[lr], c2);
            }
        }
    }
    __syncthreads();

    int f = t & 31, rl = t >> 5;
    float at = 0.f, ae = 0.f;
    for (int lr = rl; lr < SEG; lr += 16) {
        int i = j0 + lr;
        if (i < j1) {
            float si = s_s[i];
            float term = x2[i * NF + f] * si;
            at += term;
            if (si < 0.f && rnk[lr] < KEXC) ae += term;
        }
    }
    red[t] = at; __syncthreads();
    for (int s = 256; s >= 32; s >>= 1) { if (t < s) red[t] += red[t + s]; __syncthreads(); }
    if (t < 32) atomicAdd(&totf[t], red[t]);
    __syncthreads();
    red[t] = ae; __syncthreads();
    for (int s = 256; s >= 32; s >>= 1) { if (t < s) red[t] += red[t + s]; __syncthreads(); }
    if (t < 32) atomicAdd(&excf[t], red[t]);
    __syncthreads();

    if (t == 0) {
        __threadfence();
        u32 old = atomicAdd(cntg, 1u);
        s_last = (old == NB - 1) ? 1 : 0;
    }
    __syncthreads();
    if (s_last) {
        __threadfence();
        if (t < 8) {
            float o = ldv(lbp, t, tb);
            for (int ff = 0; ff < NF; ff++) {
                float tv = __hip_atomic_load(&totf[ff], __ATOMIC_RELAXED, __HIP_MEMORY_SCOPE_AGENT);
                float ev = __hip_atomic_load(&excf[ff], __ATOMIC_RELAXED, __HIP_MEMORY_SCOPE_AGENT);
                o += ((tv - ev) / KDEN) * ldv(lwp, t * 32 + ff, tb);
            }
            if (tb) ((bf16*)outp)[t] = __float2bfloat16(o);
            else    ((float*)outp)[t] = o;
        }
    }
}

extern "C" void kernel_launch(void* const* d_in, const int* in_sizes, int n_in,
                              void* d_out, int out_size, void* d_ws, size_t ws_size,
                              hipStream_t stream) {
    const void* x   = d_in[0];
    const int*  ei  = (const int*)d_in[1];
    const void* hp  = d_in[2];
    const void* ap  = d_in[3];
    const void* Wr0 = d_in[4];
    const void* Wa0 = d_in[5];
    const void* Wb0 = d_in[6];
    const void* Wr1 = d_in[7];
    const void* Wa1 = d_in[8];
    const void* Wb1 = d_in[9];
    const void* pw  = d_in[10];
    const void* lw  = d_in[11];
    const void* lb  = d_in[12];
    char* ws = (char*)d_ws;

    u32*   cntg = (u32*)(ws + OFF_CNT);
    float* totf = (float*)(ws + OFF_TOT);
    float* excf = (float*)(ws + OFF_EXC);
    u32*   pkg  = (u32*)(ws + OFF_PK);
    u32*   rstg = (u32*)(ws + OFF_RST);
    float* winv = (float*)(ws + OFF_WINV);
    float* y1a  = (float*)(ws + OFF_Y1A);
    float* y2a  = (float*)(ws + OFF_Y2A);
    float* y1b  = (float*)(ws + OFF_Y1B);
    float* y2b  = (float*)(ws + OFF_Y2B);
    float* x1T  = (float*)(ws + OFF_X1T);
    float* x2   = (float*)(ws + OFF_X2);

    hipMemsetAsync(ws, 0, ZERO_BYTES, stream);
    k_csr   <<<dim3(32), dim3(NT),  0, stream>>>(ei, hp, ap, winv, pkg, rstg);
    k_chains<<<dim3(32), dim3(NT),  0, stream>>>(x, 0, hp, pkg, rstg, winv,
                                                 Wr0, Wa0, Wb0, y1a, y2a, x1T, y1a, y2a);
    k_chains<<<dim3(32), dim3(NT),  0, stream>>>(x, 1, hp, pkg, rstg, winv,
                                                 Wr0, Wa0, Wb0, y1a, y2a, x1T, y1b, y2b);
    k_gemm  <<<dim3(47), dim3(256), 0, stream>>>(x1T, Wr1, Wa1, Wb1, y1b, y2b, x2);
    k_pool  <<<dim3(32), dim3(512), 0, stream>>>(x2, pw, lw, lb, cntg, totf, excf, d_out);
}